// Round 7
// baseline (374.967 us; speedup 1.0000x reference)
//
#include <hip/hip_runtime.h>
#include <cstdint>
#include <cstddef>

// Problem constants (fixed by the reference)
#define N_ROWS 4096
#define DIM    512
#define NCLS   30000
#define BM 256
#define BN 256
#define BK 64
#define NT2  118                    // ceil(30000/256) N-tiles
#define CPAD (NT2 * 256)            // 30208, padded classes (zero rows)
#define SPT 2                       // N-tiles per block strip
#define NSTRIPS (NT2 / SPT)         // 59
#define KT  (DIM / BK)              // 8 K-tiles per N-tile
#define NS  (SPT * KT)              // 16 K-tiles per block

typedef float  f32x4  __attribute__((ext_vector_type(4)));
typedef short  bf16x8 __attribute__((ext_vector_type(8)));
typedef unsigned int   u32;
typedef unsigned short u16;

// ---- workspace layout (bytes) ----
#define WB_BYTES   ((size_t)CPAD * DIM * 2)     // 30,932,992
#define EB_BYTES   ((size_t)N_ROWS * DIM * 2)   //  4,194,304
#define PS_BYTES   ((size_t)NT2 * N_ROWS * 4)   //  1,933,312
#define CT_BYTES   ((size_t)N_ROWS * 4)
#define BL_BYTES   (64 * 4)
#define LAB_BYTES  ((size_t)N_ROWS * 4)

#define CLIP_HI ( 1.0f - 1e-7f)
#define CLIP_LO (-1.0f + 1e-7f)
#define COSM 0.8775825618903728f    // cos(0.5)
#define SINM 0.4794255386042030f    // sin(0.5)
#define K1   92.33248261972189f     // 64*log2(e): exp(64c-64) = 2^((c-1)*K1)

__device__ __forceinline__ u16 f2bf(float f) {  // RNE float->bf16
  u32 x = __builtin_bit_cast(u32, f);
  x += 0x7fffu + ((x >> 16) & 1u);
  return (u16)(x >> 16);
}

__device__ __forceinline__ void gl_lds16(const u16* g, u16* l) {
  __builtin_amdgcn_global_load_lds((const __attribute__((address_space(1))) u32*)g,
                                   (__attribute__((address_space(3))) u32*)l,
                                   16, 0, 0);
}

// ---- label dtype probe: int64 little-endian reads as [lo,0,lo,0,...] ----
__global__ void lab_detect(const int* __restrict__ lab, int* __restrict__ flag) {
  __shared__ int s_nz;
  int tid = threadIdx.x;
  if (tid == 0) s_nz = 0;
  __syncthreads();
  int nz = 0;
  for (int i = tid; i < N_ROWS / 2; i += 1024) nz |= lab[2 * i + 1];
  if (nz) atomicOr(&s_nz, 1);
  __syncthreads();
  if (tid == 0) *flag = (s_nz == 0) ? 1 : 0;   // 1 -> int64 layout
}

__global__ void lab_fix(const int* __restrict__ lab, const int* __restrict__ flag,
                        int* __restrict__ out) {
  int i = blockIdx.x * 256 + threadIdx.x;
  out[i] = flag[0] ? lab[2 * i] : lab[i];
}

// ---- W: L2-normalize rows + cast bf16; pad rows [NCLS,CPAD) with zeros ----
__global__ void prep_w(const float* __restrict__ w, u16* __restrict__ wb) {
  int wv   = threadIdx.x >> 6;
  int lane = threadIdx.x & 63;
  int c = blockIdx.x * 4 + wv;              // one wave per class row
  u16* dst = wb + (size_t)c * DIM + lane * 8;
  if (c >= NCLS) {
    *(uint4*)dst = make_uint4(0, 0, 0, 0);
    return;
  }
  const float* src = w + (size_t)c * DIM + lane * 8;
  float4 v0 = *(const float4*)src;
  float4 v1 = *(const float4*)(src + 4);
  float a[8] = {v0.x, v0.y, v0.z, v0.w, v1.x, v1.y, v1.z, v1.w};
  float ss = 0.f;
  #pragma unroll
  for (int i = 0; i < 8; i++) ss += a[i] * a[i];
  #pragma unroll
  for (int off = 32; off; off >>= 1) ss += __shfl_xor(ss, off, 64);
  float inv = 1.0f / fmaxf(sqrtf(ss), 1e-12f);
  union { u16 h[8]; uint4 q; } pk;
  #pragma unroll
  for (int i = 0; i < 8; i++) pk.h[i] = f2bf(a[i] * inv);
  *(uint4*)dst = pk.q;
}

// ---- E: cast bf16 ----
__global__ void prep_e(const float* __restrict__ e, u16* __restrict__ eb) {
  size_t idx = ((size_t)blockIdx.x * 256 + threadIdx.x) * 8;
  float4 v0 = *(const float4*)(e + idx);
  float4 v1 = *(const float4*)(e + idx + 4);
  float a[8] = {v0.x, v0.y, v0.z, v0.w, v1.x, v1.y, v1.z, v1.w};
  union { u16 h[8]; uint4 q; } pk;
  #pragma unroll
  for (int i = 0; i < 8; i++) pk.h[i] = f2bf(a[i]);
  *(uint4*)(eb + idx) = pk.q;
}

// ---- target cosine per row, f32: dot(emb[n], w[lab[n]]/||w[lab[n]]||) ----
__global__ void tgt_k(const float* __restrict__ emb, const float* __restrict__ wts,
                      const int* __restrict__ lab, float* __restrict__ ct) {
  int w = threadIdx.x >> 6, l = threadIdx.x & 63;
  int row = blockIdx.x * 4 + w;
  int c = lab[row];
  const float* e  = emb + (size_t)row * DIM + l * 8;
  const float* wp = wts + (size_t)c   * DIM + l * 8;
  float4 e0 = *(const float4*)e,       e1 = *(const float4*)(e + 4);
  float4 w0 = *(const float4*)wp,      w1 = *(const float4*)(wp + 4);
  float dot = e0.x*w0.x + e0.y*w0.y + e0.z*w0.z + e0.w*w0.w
            + e1.x*w1.x + e1.y*w1.y + e1.z*w1.z + e1.w*w1.w;
  float ss  = w0.x*w0.x + w0.y*w0.y + w0.z*w0.z + w0.w*w0.w
            + w1.x*w1.x + w1.y*w1.y + w1.z*w1.z + w1.w*w1.w;
  #pragma unroll
  for (int off = 32; off; off >>= 1) {
    dot += __shfl_xor(dot, off, 64);
    ss  += __shfl_xor(ss,  off, 64);
  }
  if (l == 0) ct[row] = dot / fmaxf(sqrtf(ss), 1e-12f);
}

// ---- fused GEMM + clip + partial sum-exp (fixed max = 64), 256x256 tile ----
// A-fragments load DIRECTLY from global (L1-resident 16 KB k-slab per block,
// full 128-B line consumed per k-tile) -> A never staged through LDS.
// B only in LDS: 2-buffer dbuf (64 KB), 4 gl_lds chunks per k-tile issued in
// two pairs; counted vmcnt(2) keeps the prefetch pairs in flight; asm memory
// fences pin the a-load / stage / ds_read group order for correct counting.
__global__ __launch_bounds__(512, 1) void arc_main(
    const u16* __restrict__ eb, const u16* __restrict__ wb,
    float* __restrict__ psum)
{
  __shared__ __align__(16) u16 lB[2][BN * BK];   // 2 x 32 KB
  __shared__ float ep[4][BM];
  const int t  = threadIdx.x;
  const int l  = t & 63;
  const int w  = t >> 6;
  const int wm = w >> 2, wn = w & 3;
  const int cl = l & 15, bq = l >> 4;
  const int mi    = blockIdx.x & 15;    // m inner: concurrent blocks share E in L2/L3
  const int strip = blockIdx.x >> 4;
  const int rowbase = mi * BM;
  const int n0s = strip * SPT;

  // A-frag global element offsets (relative to ebR): row = wm*128+m*16+cl,
  // col chunk bq*8; per use add kt*64 + kk*32.
  u32 au[8];
  #pragma unroll
  for (int m = 0; m < 8; m++)
    au[m] = (u32)(wm * 128 + m * 16 + cl) * DIM + bq * 8;
  const u16* ebR = eb + (size_t)rowbase * DIM;

  // B frag LDS offsets; 16B-slot swizzle slot' = slot ^ (r&7)  (R6-verified)
  u32 boff[8];
  #pragma unroll
  for (int s = 0; s < 2; s++)
    #pragma unroll
    for (int n = 0; n < 4; n++) {
      int r = wn * 64 + n * 16 + cl;
      boff[s * 4 + n] = (u32)r * BK + (((s * 4 + bq) ^ (r & 7)) << 3);
    }

  // B staging: 4 chunks of 8 KB (64 rows each) over 512 threads; linear LDS
  // dest + inverse-swizzled global source (same involution as the read).
  u32 goff[4];
  #pragma unroll
  for (int c = 0; c < 4; c++) {
    int rl = c * 64 + (t >> 3);
    goff[c] = (u32)rl * DIM + (((t & 7) ^ (rl & 7)) << 3);
  }

  f32x4 acc[8][4];
  #pragma unroll
  for (int m = 0; m < 8; m++)
    #pragma unroll
    for (int n = 0; n < 4; n++)
      #pragma unroll
      for (int q = 0; q < 4; q++) acc[m][n][q] = 0.f;

  // prologue: stage B k-tile 0 into buf 0
  {
    const u32 bb0 = (u32)n0s * (BN * DIM);
    #pragma unroll
    for (int c = 0; c < 4; c++)
      gl_lds16(wb + bb0 + goff[c], &lB[0][c * 4096 + w * 512]);
  }

  for (int u = 0; u < NS; u++) {
    const u16* Bs = &lB[u & 1][0];
    u16* Bn = &lB[(u + 1) & 1][0];
    const bool st = (u + 1 < NS);
    const u32 ka  = (u32)(u & 7) * BK;
    const u32 bbn = (u32)(n0s + ((u + 1) >> 3)) * (BN * DIM) + (u32)((u + 1) & 7) * BK;

    asm volatile("s_waitcnt vmcnt(0)" ::: "memory");  // B(u)'s 4 chunks landed
    __builtin_amdgcn_s_barrier();                     // ..for ALL waves
    asm volatile("" ::: "memory");

    uint4  av[8];
    bf16x8 bg[4];

    // ---- kk = 0: a-loads; stage B(u+1) chunks 0-1; b-frags; MFMA ----
    #pragma unroll
    for (int m = 0; m < 8; m++)
      av[m] = *(const uint4*)(ebR + au[m] + ka);
    asm volatile("" ::: "memory");
    if (st) {
      gl_lds16(wb + bbn + goff[0], &Bn[0 * 4096 + w * 512]);
      gl_lds16(wb + bbn + goff[1], &Bn[1 * 4096 + w * 512]);
    }
    asm volatile("" ::: "memory");
    #pragma unroll
    for (int n = 0; n < 4; n++) bg[n] = *(const bf16x8*)&Bs[boff[n]];
    asm volatile("s_waitcnt vmcnt(2)" ::: "memory");   // a-loads done; 2 stages fly
    __builtin_amdgcn_s_setprio(1);
    #pragma unroll
    for (int m = 0; m < 8; m++)
      #pragma unroll
      for (int n = 0; n < 4; n++)
        acc[m][n] = __builtin_amdgcn_mfma_f32_16x16x32_bf16(
            __builtin_bit_cast(bf16x8, av[m]), bg[n], acc[m][n], 0, 0, 0);
    __builtin_amdgcn_s_setprio(0);

    // ---- kk = 1: a-loads; stage B(u+1) chunks 2-3; b-frags; MFMA ----
    #pragma unroll
    for (int m = 0; m < 8; m++)
      av[m] = *(const uint4*)(ebR + au[m] + ka + 32);
    asm volatile("" ::: "memory");
    if (st) {
      gl_lds16(wb + bbn + goff[2], &Bn[2 * 4096 + w * 512]);
      gl_lds16(wb + bbn + goff[3], &Bn[3 * 4096 + w * 512]);
    }
    asm volatile("" ::: "memory");
    #pragma unroll
    for (int n = 0; n < 4; n++) bg[n] = *(const bf16x8*)&Bs[boff[4 + n]];
    asm volatile("s_waitcnt vmcnt(2)" ::: "memory");   // a-kk1 done; 2 stages fly
    __builtin_amdgcn_s_setprio(1);
    #pragma unroll
    for (int m = 0; m < 8; m++)
      #pragma unroll
      for (int n = 0; n < 4; n++)
        acc[m][n] = __builtin_amdgcn_mfma_f32_16x16x32_bf16(
            __builtin_bit_cast(bf16x8, av[m]), bg[n], acc[m][n], 0, 0, 0);
    __builtin_amdgcn_s_setprio(0);
    __builtin_amdgcn_s_barrier();   // all waves done reading Bs before overwrite

    if ((u & 7) == 7) {
      // epilogue for N-tile nt: clip, exp2, sum over wave's 64 cols,
      // cross-wn merge via LDS, one psum row-partial per N-tile.
      const int nt = n0s + (u >> 3);
      #pragma unroll
      for (int m = 0; m < 8; m++) {
        #pragma unroll
        for (int q = 0; q < 4; q++) {
          float s = 0.f;
          #pragma unroll
          for (int n = 0; n < 4; n++) {
            float tc = __builtin_amdgcn_fmed3f(acc[m][n][q], CLIP_LO, CLIP_HI);
            s += __builtin_amdgcn_exp2f(__builtin_fmaf(tc, K1, -K1));
            acc[m][n][q] = 0.f;
          }
          s += __shfl_xor(s, 1, 64);
          s += __shfl_xor(s, 2, 64);
          s += __shfl_xor(s, 4, 64);
          s += __shfl_xor(s, 8, 64);
          if ((l & 15) == 0) ep[wn][wm * 128 + m * 16 + (l >> 4) * 4 + q] = s;
        }
      }
      asm volatile("s_waitcnt lgkmcnt(0)" ::: "memory");
      __builtin_amdgcn_s_barrier();
      asm volatile("" ::: "memory");
      if (l < 32) {
        int r = w * 32 + l;
        float v = ep[0][r] + ep[1][r] + ep[2][r] + ep[3][r];
        psum[(size_t)nt * N_ROWS + rowbase + r] = v;
      }
      __builtin_amdgcn_s_barrier();   // ep reads done before next tile's writes
    }
  }
}

// ---- per-row LSE merge + margin swap + per-block loss sums ----
__global__ void arc_finish1(const float* __restrict__ psum, const float* __restrict__ ct,
                            float* __restrict__ bl) {
  int tid = threadIdx.x;
  int row = blockIdx.x * 256 + tid;
  float S = 0.f;
  for (int p = 0; p < NT2; p++) S += psum[(size_t)p * N_ROWS + row];
  float c  = __builtin_amdgcn_fmed3f(ct[row], CLIP_LO, CLIP_HI);
  float cm = c * COSM - sqrtf(fmaxf(1.0f - c * c, 0.0f)) * SINM;
  // swap the target's no-margin term for the margin term (both vs fixed max 64)
  float S2 = S - __builtin_amdgcn_exp2f(__builtin_fmaf(c,  K1, -K1))
               + __builtin_amdgcn_exp2f(__builtin_fmaf(cm, K1, -K1));
  float loss = 64.0f + __builtin_amdgcn_logf(S2) * 0.6931471805599453f - 64.0f * cm;
  #pragma unroll
  for (int off = 32; off; off >>= 1) loss += __shfl_xor(loss, off, 64);
  __shared__ float red[4];
  if ((tid & 63) == 0) red[tid >> 6] = loss;
  __syncthreads();
  if (tid == 0) bl[blockIdx.x] = red[0] + red[1] + red[2] + red[3];
}

__global__ void arc_finish2(const float* __restrict__ bl, float* __restrict__ out) {
  if (threadIdx.x == 0) {
    float t = 0.f;
    for (int i = 0; i < N_ROWS / 256; i++) t += bl[i];
    out[0] = t * (1.0f / (float)N_ROWS);
  }
}

extern "C" void kernel_launch(void* const* d_in, const int* in_sizes, int n_in,
                              void* d_out, int out_size, void* d_ws, size_t ws_size,
                              hipStream_t stream) {
  const float* emb   = (const float*)d_in[0];
  const int*   lab   = (const int*)d_in[1];
  const float* wts   = (const float*)d_in[2];

  char* ws = (char*)d_ws;
  u16*   wb    = (u16*)(ws);
  u16*   eb    = (u16*)(ws + WB_BYTES);
  float* psum  = (float*)(ws + WB_BYTES + EB_BYTES);
  float* ct    = (float*)(ws + WB_BYTES + EB_BYTES + PS_BYTES);
  float* bl    = (float*)(ws + WB_BYTES + EB_BYTES + PS_BYTES + CT_BYTES);
  int*   lab32 = (int*)  (ws + WB_BYTES + EB_BYTES + PS_BYTES + CT_BYTES + BL_BYTES);
  int*   flag  = (int*)  (ws + WB_BYTES + EB_BYTES + PS_BYTES + CT_BYTES + BL_BYTES + LAB_BYTES);
  // total ~37.1 MiB of d_ws assumed available

  lab_detect<<<dim3(1), dim3(1024), 0, stream>>>(lab, flag);
  lab_fix<<<dim3(N_ROWS / 256), dim3(256), 0, stream>>>(lab, flag, lab32);
  prep_w<<<dim3(CPAD / 4), dim3(256), 0, stream>>>(wts, wb);
  prep_e<<<dim3((N_ROWS * DIM / 8) / 256), dim3(256), 0, stream>>>(emb, eb);
  tgt_k<<<dim3(N_ROWS / 4), dim3(256), 0, stream>>>(emb, wts, lab32, ct);
  arc_main<<<dim3(16 * NSTRIPS), dim3(512), 0, stream>>>(eb, wb, psum);
  arc_finish1<<<dim3(N_ROWS / 256), dim3(256), 0, stream>>>(psum, ct, bl);
  arc_finish2<<<dim3(1), dim3(64), 0, stream>>>(bl, (float*)d_out);
}

// Round 8
// 240.640 us; speedup vs baseline: 1.5582x; 1.5582x over previous
//
#include <hip/hip_runtime.h>
#include <cstdint>
#include <cstddef>

// Problem constants (fixed by the reference)
#define N_ROWS 4096
#define DIM    512
#define NCLS   30000
#define BM 128
#define BN 256
#define BK 32
#define NT2  118                    // ceil(30000/256) N-tiles
#define CPAD (NT2 * 256)            // 30208, padded classes (zero rows)
#define MI   (N_ROWS / BM)          // 32 m-tiles
#define KS   (DIM / BK)             // 16 k-steps per block

typedef float  f32x4  __attribute__((ext_vector_type(4)));
typedef short  bf16x8 __attribute__((ext_vector_type(8)));
typedef unsigned int   u32;
typedef unsigned short u16;

// ---- workspace layout (bytes) ----
#define WB_BYTES   ((size_t)CPAD * DIM * 2)     // 30,932,992
#define EB_BYTES   ((size_t)N_ROWS * DIM * 2)   //  4,194,304
#define PS_BYTES   ((size_t)NT2 * N_ROWS * 4)   //  1,933,312
#define CT_BYTES   ((size_t)N_ROWS * 4)
#define BL_BYTES   (64 * 4)
#define LAB_BYTES  ((size_t)N_ROWS * 4)

#define CLIP_HI ( 1.0f - 1e-7f)
#define CLIP_LO (-1.0f + 1e-7f)
#define COSM 0.8775825618903728f    // cos(0.5)
#define SINM 0.4794255386042030f    // sin(0.5)
#define K1   92.33248261972189f     // 64*log2(e): exp(64c-64) = 2^((c-1)*K1)

__device__ __forceinline__ u16 f2bf(float f) {  // RNE float->bf16
  u32 x = __builtin_bit_cast(u32, f);
  x += 0x7fffu + ((x >> 16) & 1u);
  return (u16)(x >> 16);
}

__device__ __forceinline__ void gl_lds16(const u16* g, u16* l) {
  __builtin_amdgcn_global_load_lds((const __attribute__((address_space(1))) u32*)g,
                                   (__attribute__((address_space(3))) u32*)l,
                                   16, 0, 0);
}

// ---- label dtype probe: int64 little-endian reads as [lo,0,lo,0,...] ----
__global__ void lab_detect(const int* __restrict__ lab, int* __restrict__ flag) {
  __shared__ int s_nz;
  int tid = threadIdx.x;
  if (tid == 0) s_nz = 0;
  __syncthreads();
  int nz = 0;
  for (int i = tid; i < N_ROWS / 2; i += 1024) nz |= lab[2 * i + 1];
  if (nz) atomicOr(&s_nz, 1);
  __syncthreads();
  if (tid == 0) *flag = (s_nz == 0) ? 1 : 0;   // 1 -> int64 layout
}

__global__ void lab_fix(const int* __restrict__ lab, const int* __restrict__ flag,
                        int* __restrict__ out) {
  int i = blockIdx.x * 256 + threadIdx.x;
  out[i] = flag[0] ? lab[2 * i] : lab[i];
}

// ---- W: L2-normalize rows + cast bf16; pad rows [NCLS,CPAD) with zeros ----
__global__ void prep_w(const float* __restrict__ w, u16* __restrict__ wb) {
  int wv   = threadIdx.x >> 6;
  int lane = threadIdx.x & 63;
  int c = blockIdx.x * 4 + wv;              // one wave per class row
  u16* dst = wb + (size_t)c * DIM + lane * 8;
  if (c >= NCLS) {
    *(uint4*)dst = make_uint4(0, 0, 0, 0);
    return;
  }
  const float* src = w + (size_t)c * DIM + lane * 8;
  float4 v0 = *(const float4*)src;
  float4 v1 = *(const float4*)(src + 4);
  float a[8] = {v0.x, v0.y, v0.z, v0.w, v1.x, v1.y, v1.z, v1.w};
  float ss = 0.f;
  #pragma unroll
  for (int i = 0; i < 8; i++) ss += a[i] * a[i];
  #pragma unroll
  for (int off = 32; off; off >>= 1) ss += __shfl_xor(ss, off, 64);
  float inv = 1.0f / fmaxf(sqrtf(ss), 1e-12f);
  union { u16 h[8]; uint4 q; } pk;
  #pragma unroll
  for (int i = 0; i < 8; i++) pk.h[i] = f2bf(a[i] * inv);
  *(uint4*)dst = pk.q;
}

// ---- E: cast bf16 ----
__global__ void prep_e(const float* __restrict__ e, u16* __restrict__ eb) {
  size_t idx = ((size_t)blockIdx.x * 256 + threadIdx.x) * 8;
  float4 v0 = *(const float4*)(e + idx);
  float4 v1 = *(const float4*)(e + idx + 4);
  float a[8] = {v0.x, v0.y, v0.z, v0.w, v1.x, v1.y, v1.z, v1.w};
  union { u16 h[8]; uint4 q; } pk;
  #pragma unroll
  for (int i = 0; i < 8; i++) pk.h[i] = f2bf(a[i]);
  *(uint4*)(eb + idx) = pk.q;
}

// ---- target cosine per row, f32: dot(emb[n], w[lab[n]]/||w[lab[n]]||) ----
__global__ void tgt_k(const float* __restrict__ emb, const float* __restrict__ wts,
                      const int* __restrict__ lab, float* __restrict__ ct) {
  int w = threadIdx.x >> 6, l = threadIdx.x & 63;
  int row = blockIdx.x * 4 + w;
  int c = lab[row];
  const float* e  = emb + (size_t)row * DIM + l * 8;
  const float* wp = wts + (size_t)c   * DIM + l * 8;
  float4 e0 = *(const float4*)e,       e1 = *(const float4*)(e + 4);
  float4 w0 = *(const float4*)wp,      w1 = *(const float4*)(wp + 4);
  float dot = e0.x*w0.x + e0.y*w0.y + e0.z*w0.z + e0.w*w0.w
            + e1.x*w1.x + e1.y*w1.y + e1.z*w1.z + e1.w*w1.w;
  float ss  = w0.x*w0.x + w0.y*w0.y + w0.z*w0.z + w0.w*w0.w
            + w1.x*w1.x + w1.y*w1.y + w1.z*w1.z + w1.w*w1.w;
  #pragma unroll
  for (int off = 32; off; off >>= 1) {
    dot += __shfl_xor(dot, off, 64);
    ss  += __shfl_xor(ss,  off, 64);
  }
  if (l == 0) ct[row] = dot / fmaxf(sqrtf(ss), 1e-12f);
}

// ---- fused GEMM + clip + partial sum-exp (fixed max = 64), 128x256 tile ----
// m97-structure: 256 threads (4 waves, 1m x 4n), dbuf LDS 48 KB -> 3 blocks/CU.
// Inter-block TLP decouples LDS/stage/MFMA phases (no cross-block barriers).
// One barrier + vmcnt(0) per k-step; stage(u+1) after the barrier (race-free:
// buf[(u+1)&1]'s readers finished at that same barrier). Single epilogue.
__global__ __launch_bounds__(256) void arc_main(
    const u16* __restrict__ eb, const u16* __restrict__ wb,
    float* __restrict__ psum)
{
  __shared__ __align__(16) u16 lds[2][(BM + BN) * BK];  // A:[128][32] B:[256][32]
  __shared__ float ep[4][BM];
  const int t  = threadIdx.x;
  const int l  = t & 63;
  const int w  = t >> 6;          // wave = n-position (4 x 64 cols)
  const int cl = l & 15, bq = l >> 4;
  const int mi    = blockIdx.x & (MI - 1);   // m inner: neighbors share W N-tile
  const int strip = blockIdx.x >> 5;         // N-tile 0..117
  const int rowbase = mi * BM;

  // frag LDS elem offsets; slot' = slot ^ ((r>>1)&3) -> 2-way (free, R5-verified)
  u32 aoff[8], boff[4];
  #pragma unroll
  for (int m = 0; m < 8; m++) {
    int r = m * 16 + cl;
    aoff[m] = (u32)r * BK + ((bq ^ ((r >> 1) & 3)) << 3);
  }
  #pragma unroll
  for (int n = 0; n < 4; n++) {
    int r = w * 64 + n * 16 + cl;
    boff[n] = (u32)(BM * BK) + (u32)r * BK + ((bq ^ ((r >> 1) & 3)) << 3);
  }

  // staging offsets: linear LDS dest + inverse-swizzled global src (rule 21).
  // A: 2 chunks/wave (16 rows each); B: 4 chunks/wave.
  u32 ga[2], gb[4];
  #pragma unroll
  for (int i = 0; i < 2; i++) {
    int rl = (w * 2 + i) * 16 + (l >> 2);
    ga[i] = (u32)rl * DIM + (((l & 3) ^ ((rl >> 1) & 3)) << 3);
  }
  #pragma unroll
  for (int j = 0; j < 4; j++) {
    int rl = (w * 4 + j) * 16 + (l >> 2);
    gb[j] = (u32)rl * DIM + (((l & 3) ^ ((rl >> 1) & 3)) << 3);
  }
  const u16* ebR = eb + (size_t)rowbase * DIM;
  const u16* wbN = wb + (size_t)strip * BN * DIM;

  f32x4 acc[8][4];
  #pragma unroll
  for (int m = 0; m < 8; m++)
    #pragma unroll
    for (int n = 0; n < 4; n++)
      #pragma unroll
      for (int q = 0; q < 4; q++) acc[m][n][q] = 0.f;

  // prologue: stage k-step 0 into buf 0
  #pragma unroll
  for (int i = 0; i < 2; i++) gl_lds16(ebR + ga[i], &lds[0][(w * 2 + i) * 512]);
  #pragma unroll
  for (int j = 0; j < 4; j++) gl_lds16(wbN + gb[j], &lds[0][BM * BK + (w * 4 + j) * 512]);

  for (int u = 0; u < KS; u++) {
    asm volatile("s_waitcnt vmcnt(0)" ::: "memory");  // step u's 6 chunks landed
    __builtin_amdgcn_s_barrier();                     // ..for ALL waves
    asm volatile("" ::: "memory");

    if (u + 1 < KS) {      // stage u+1 into the other buf (its readers are done)
      const u32 ko = (u32)(u + 1) * BK;
      u16* Ad = &lds[(u + 1) & 1][0];
      u16* Bd = &lds[(u + 1) & 1][BM * BK];
      #pragma unroll
      for (int i = 0; i < 2; i++) gl_lds16(ebR + ko + ga[i], Ad + (w * 2 + i) * 512);
      #pragma unroll
      for (int j = 0; j < 4; j++) gl_lds16(wbN + ko + gb[j], Bd + (w * 4 + j) * 512);
    }

    const u16* Ls = &lds[u & 1][0];
    bf16x8 af[8], bg[4];
    #pragma unroll
    for (int m = 0; m < 8; m++) af[m] = *(const bf16x8*)&Ls[aoff[m]];
    #pragma unroll
    for (int n = 0; n < 4; n++) bg[n] = *(const bf16x8*)&Ls[boff[n]];

    __builtin_amdgcn_s_setprio(1);
    #pragma unroll
    for (int m = 0; m < 8; m++)
      #pragma unroll
      for (int n = 0; n < 4; n++)
        acc[m][n] = __builtin_amdgcn_mfma_f32_16x16x32_bf16(af[m], bg[n], acc[m][n], 0, 0, 0);
    __builtin_amdgcn_s_setprio(0);
  }

  // epilogue: clip, exp2, sum over this wave's 64 cols, cross-wave merge,
  // one psum row-partial for this (strip, mi).
  #pragma unroll
  for (int m = 0; m < 8; m++) {
    #pragma unroll
    for (int q = 0; q < 4; q++) {
      float s = 0.f;
      #pragma unroll
      for (int n = 0; n < 4; n++) {
        float tc = __builtin_amdgcn_fmed3f(acc[m][n][q], CLIP_LO, CLIP_HI);
        s += __builtin_amdgcn_exp2f(__builtin_fmaf(tc, K1, -K1));
      }
      s += __shfl_xor(s, 1, 64);
      s += __shfl_xor(s, 2, 64);
      s += __shfl_xor(s, 4, 64);
      s += __shfl_xor(s, 8, 64);
      if ((l & 15) == 0) ep[w][m * 16 + (l >> 4) * 4 + q] = s;
    }
  }
  __syncthreads();
  if (t < BM) {
    float v = ep[0][t] + ep[1][t] + ep[2][t] + ep[3][t];
    psum[(size_t)strip * N_ROWS + rowbase + t] = v;
  }
}

// ---- per-row LSE merge + margin swap + per-block loss sums ----
__global__ void arc_finish1(const float* __restrict__ psum, const float* __restrict__ ct,
                            float* __restrict__ bl) {
  int tid = threadIdx.x;
  int row = blockIdx.x * 256 + tid;
  float S = 0.f;
  for (int p = 0; p < NT2; p++) S += psum[(size_t)p * N_ROWS + row];
  float c  = __builtin_amdgcn_fmed3f(ct[row], CLIP_LO, CLIP_HI);
  float cm = c * COSM - sqrtf(fmaxf(1.0f - c * c, 0.0f)) * SINM;
  // swap the target's no-margin term for the margin term (both vs fixed max 64)
  float S2 = S - __builtin_amdgcn_exp2f(__builtin_fmaf(c,  K1, -K1))
               + __builtin_amdgcn_exp2f(__builtin_fmaf(cm, K1, -K1));
  float loss = 64.0f + __builtin_amdgcn_logf(S2) * 0.6931471805599453f - 64.0f * cm;
  #pragma unroll
  for (int off = 32; off; off >>= 1) loss += __shfl_xor(loss, off, 64);
  __shared__ float red[4];
  if ((tid & 63) == 0) red[tid >> 6] = loss;
  __syncthreads();
  if (tid == 0) bl[blockIdx.x] = red[0] + red[1] + red[2] + red[3];
}

__global__ void arc_finish2(const float* __restrict__ bl, float* __restrict__ out) {
  if (threadIdx.x == 0) {
    float t = 0.f;
    for (int i = 0; i < N_ROWS / 256; i++) t += bl[i];
    out[0] = t * (1.0f / (float)N_ROWS);
  }
}

extern "C" void kernel_launch(void* const* d_in, const int* in_sizes, int n_in,
                              void* d_out, int out_size, void* d_ws, size_t ws_size,
                              hipStream_t stream) {
  const float* emb   = (const float*)d_in[0];
  const int*   lab   = (const int*)d_in[1];
  const float* wts   = (const float*)d_in[2];

  char* ws = (char*)d_ws;
  u16*   wb    = (u16*)(ws);
  u16*   eb    = (u16*)(ws + WB_BYTES);
  float* psum  = (float*)(ws + WB_BYTES + EB_BYTES);
  float* ct    = (float*)(ws + WB_BYTES + EB_BYTES + PS_BYTES);
  float* bl    = (float*)(ws + WB_BYTES + EB_BYTES + PS_BYTES + CT_BYTES);
  int*   lab32 = (int*)  (ws + WB_BYTES + EB_BYTES + PS_BYTES + CT_BYTES + BL_BYTES);
  int*   flag  = (int*)  (ws + WB_BYTES + EB_BYTES + PS_BYTES + CT_BYTES + BL_BYTES + LAB_BYTES);
  // total ~37.1 MiB of d_ws assumed available

  lab_detect<<<dim3(1), dim3(1024), 0, stream>>>(lab, flag);
  lab_fix<<<dim3(N_ROWS / 256), dim3(256), 0, stream>>>(lab, flag, lab32);
  prep_w<<<dim3(CPAD / 4), dim3(256), 0, stream>>>(wts, wb);
  prep_e<<<dim3((N_ROWS * DIM / 8) / 256), dim3(256), 0, stream>>>(emb, eb);
  tgt_k<<<dim3(N_ROWS / 4), dim3(256), 0, stream>>>(emb, wts, lab32, ct);
  arc_main<<<dim3(NT2 * MI), dim3(256), 0, stream>>>(eb, wb, psum);
  arc_finish1<<<dim3(N_ROWS / 256), dim3(256), 0, stream>>>(psum, ct, bl);
  arc_finish2<<<dim3(1), dim3(64), 0, stream>>>(bl, (float*)d_out);
}

// Round 9
// 216.714 us; speedup vs baseline: 1.7302x; 1.1104x over previous
//
#include <hip/hip_runtime.h>
#include <cstdint>
#include <cstddef>

// Problem constants (fixed by the reference)
#define N_ROWS 4096
#define DIM    512
#define NCLS   30000
#define BM 256
#define BN 256
#define BK 64
#define NT2  118                    // ceil(30000/256) N-tiles
#define CPAD (NT2 * 256)            // 30208, padded classes (zero rows)
#define SPT 2                       // N-tiles per block strip
#define NSTRIPS (NT2 / SPT)         // 59
#define NS  (SPT * (DIM / BK))      // 16 K-tiles per block

typedef float  f32x4  __attribute__((ext_vector_type(4)));
typedef short  bf16x8 __attribute__((ext_vector_type(8)));
typedef unsigned int   u32;
typedef unsigned short u16;

// ---- workspace layout (bytes) ----
#define WB_BYTES   ((size_t)CPAD * DIM * 2)     // 30,932,992
#define EB_BYTES   ((size_t)N_ROWS * DIM * 2)   //  4,194,304
#define PS_BYTES   ((size_t)NT2 * N_ROWS * 4)   //  1,933,312
#define CT_BYTES   ((size_t)N_ROWS * 4)
#define BL_BYTES   (64 * 4)
#define LAB_BYTES  ((size_t)N_ROWS * 4)

#define CLIP_HI ( 1.0f - 1e-7f)
#define CLIP_LO (-1.0f + 1e-7f)
#define COSM 0.8775825618903728f    // cos(0.5)
#define SINM 0.4794255386042030f    // sin(0.5)
#define K1   92.33248261972189f     // 64*log2(e): exp(64c-64) = 2^((c-1)*K1)

__device__ __forceinline__ u16 f2bf(float f) {  // RNE float->bf16
  u32 x = __builtin_bit_cast(u32, f);
  x += 0x7fffu + ((x >> 16) & 1u);
  return (u16)(x >> 16);
}

__device__ __forceinline__ void gl_lds16(const u16* g, u16* l) {
  __builtin_amdgcn_global_load_lds((const __attribute__((address_space(1))) u32*)g,
                                   (__attribute__((address_space(3))) u32*)l,
                                   16, 0, 0);
}

// ---- label dtype probe: int64 little-endian reads as [lo,0,lo,0,...] ----
__global__ void lab_detect(const int* __restrict__ lab, int* __restrict__ flag) {
  __shared__ int s_nz;
  int tid = threadIdx.x;
  if (tid == 0) s_nz = 0;
  __syncthreads();
  int nz = 0;
  for (int i = tid; i < N_ROWS / 2; i += 1024) nz |= lab[2 * i + 1];
  if (nz) atomicOr(&s_nz, 1);
  __syncthreads();
  if (tid == 0) *flag = (s_nz == 0) ? 1 : 0;   // 1 -> int64 layout
}

__global__ void lab_fix(const int* __restrict__ lab, const int* __restrict__ flag,
                        int* __restrict__ out) {
  int i = blockIdx.x * 256 + threadIdx.x;
  out[i] = flag[0] ? lab[2 * i] : lab[i];
}

// ---- W: L2-normalize rows + cast bf16; pad rows [NCLS,CPAD) with zeros ----
__global__ void prep_w(const float* __restrict__ w, u16* __restrict__ wb) {
  int wv   = threadIdx.x >> 6;
  int lane = threadIdx.x & 63;
  int c = blockIdx.x * 4 + wv;              // one wave per class row
  u16* dst = wb + (size_t)c * DIM + lane * 8;
  if (c >= NCLS) {
    *(uint4*)dst = make_uint4(0, 0, 0, 0);
    return;
  }
  const float* src = w + (size_t)c * DIM + lane * 8;
  float4 v0 = *(const float4*)src;
  float4 v1 = *(const float4*)(src + 4);
  float a[8] = {v0.x, v0.y, v0.z, v0.w, v1.x, v1.y, v1.z, v1.w};
  float ss = 0.f;
  #pragma unroll
  for (int i = 0; i < 8; i++) ss += a[i] * a[i];
  #pragma unroll
  for (int off = 32; off; off >>= 1) ss += __shfl_xor(ss, off, 64);
  float inv = 1.0f / fmaxf(sqrtf(ss), 1e-12f);
  union { u16 h[8]; uint4 q; } pk;
  #pragma unroll
  for (int i = 0; i < 8; i++) pk.h[i] = f2bf(a[i] * inv);
  *(uint4*)dst = pk.q;
}

// ---- E: cast bf16 ----
__global__ void prep_e(const float* __restrict__ e, u16* __restrict__ eb) {
  size_t idx = ((size_t)blockIdx.x * 256 + threadIdx.x) * 8;
  float4 v0 = *(const float4*)(e + idx);
  float4 v1 = *(const float4*)(e + idx + 4);
  float a[8] = {v0.x, v0.y, v0.z, v0.w, v1.x, v1.y, v1.z, v1.w};
  union { u16 h[8]; uint4 q; } pk;
  #pragma unroll
  for (int i = 0; i < 8; i++) pk.h[i] = f2bf(a[i]);
  *(uint4*)(eb + idx) = pk.q;
}

// ---- target cosine per row, f32: dot(emb[n], w[lab[n]]/||w[lab[n]]||) ----
__global__ void tgt_k(const float* __restrict__ emb, const float* __restrict__ wts,
                      const int* __restrict__ lab, float* __restrict__ ct) {
  int w = threadIdx.x >> 6, l = threadIdx.x & 63;
  int row = blockIdx.x * 4 + w;
  int c = lab[row];
  const float* e  = emb + (size_t)row * DIM + l * 8;
  const float* wp = wts + (size_t)c   * DIM + l * 8;
  float4 e0 = *(const float4*)e,       e1 = *(const float4*)(e + 4);
  float4 w0 = *(const float4*)wp,      w1 = *(const float4*)(wp + 4);
  float dot = e0.x*w0.x + e0.y*w0.y + e0.z*w0.z + e0.w*w0.w
            + e1.x*w1.x + e1.y*w1.y + e1.z*w1.z + e1.w*w1.w;
  float ss  = w0.x*w0.x + w0.y*w0.y + w0.z*w0.z + w0.w*w0.w
            + w1.x*w1.x + w1.y*w1.y + w1.z*w1.z + w1.w*w1.w;
  #pragma unroll
  for (int off = 32; off; off >>= 1) {
    dot += __shfl_xor(dot, off, 64);
    ss  += __shfl_xor(ss,  off, 64);
  }
  if (l == 0) ct[row] = dot / fmaxf(sqrtf(ss), 1e-12f);
}

// ---- fused GEMM + clip + partial sum-exp (fixed max = 64), 256x256 tile ----
// R6's 4-phase/K-tile schedule + K-half chunking + COUNTED vmcnt (T4, m218):
// chunks are 128 rows x 32 cols (8 KB). Stage order for tile u+1 during u:
//   p0: A-k0 (2 chunks), p1: B-k0, p2: A-k1, p3: B-k1.
// Consumption: tile u+1 p0 reads k0 chunks, p2 reads k1 chunks.
// vmcnt(4) at p1 and p3 -> every chunk provably lands >=2 phases before its
// first read, while 2 chunks (4 loads) ALWAYS stay in flight (never drain 0).
// Epilogue tiles use __syncthreads (full drain, resets the count invariant).
__global__ __launch_bounds__(512, 1) void arc_main(
    const u16* __restrict__ eb, const u16* __restrict__ wb,
    float* __restrict__ psum)
{
  __shared__ __align__(16) u16 lds[2 * 32768];  // 2 sets x (A 32KB + B 32KB)
  __shared__ float ep[4][BM];
  const int t  = threadIdx.x;
  const int l  = t & 63;
  const int w  = t >> 6;
  const int wm = w >> 2, wn = w & 3;
  const int cl = l & 15, bq = l >> 4;
  const int mi    = blockIdx.x & 15;    // m inner: concurrent blocks share E
  const int strip = blockIdx.x >> 4;
  const int rowbase = mi * BM;
  const int n0s = strip * SPT;

  // frag LDS elem offsets (chunk-local): chunk (kh,rh) at (kh*2+rh)*4096;
  // within: r'*32 + slot*8, slot = bq ^ ((r'>>1)&3)  (R5-verified 2-way-free)
  u32 aoff[2][8], boff[2][4];
  #pragma unroll
  for (int kk = 0; kk < 2; kk++) {
    #pragma unroll
    for (int m = 0; m < 8; m++) {
      int rp = m * 16 + cl;                      // row within A chunk (rh = wm)
      aoff[kk][m] = (u32)(kk * 2 + wm) * 4096 + rp * 32 + ((bq ^ ((rp >> 1) & 3)) << 3);
    }
    #pragma unroll
    for (int n = 0; n < 4; n++) {
      int rp = (wn & 1) * 64 + n * 16 + cl;      // row within B chunk (rh = wn>>1)
      boff[kk][n] = 16384u + (u32)(kk * 2 + (wn >> 1)) * 4096 + rp * 32 + ((bq ^ ((rp >> 1) & 3)) << 3);
    }
  }

  // stage global offsets: thread t covers chunk row sr = t>>2, 16B slot t&3;
  // inverse-swizzled global source (same involution as the frag read).
  const int sr = t >> 2;
  const u32 ssl = (u32)(((t & 3) ^ ((sr >> 1) & 3)) << 3);
  const u32 gA0 = (u32)(0 * 128 + sr) * DIM + ssl;
  const u32 gA1 = (u32)(1 * 128 + sr) * DIM + ssl;
  const u16* ebR = eb + (size_t)rowbase * DIM;

  f32x4 acc[8][4];
  #pragma unroll
  for (int m = 0; m < 8; m++)
    #pragma unroll
    for (int n = 0; n < 4; n++)
      #pragma unroll
      for (int q = 0; q < 4; q++) acc[m][n][q] = 0.f;

  // prologue: stage K-tile 0 (8 chunks) into set 0, full drain once
  {
    const u32 bb = (u32)n0s * (BN * DIM);
    #pragma unroll
    for (int kh = 0; kh < 2; kh++) {
      gl_lds16(ebR + kh * 32 + gA0, &lds[(kh * 2 + 0) * 4096 + t * 8]);
      gl_lds16(ebR + kh * 32 + gA1, &lds[(kh * 2 + 1) * 4096 + t * 8]);
      gl_lds16(wb + bb + kh * 32 + gA0, &lds[16384 + (kh * 2 + 0) * 4096 + t * 8]);
      gl_lds16(wb + bb + kh * 32 + gA1, &lds[16384 + (kh * 2 + 1) * 4096 + t * 8]);
    }
  }
  asm volatile("s_waitcnt vmcnt(0)" ::: "memory");
  __builtin_amdgcn_s_barrier();
  asm volatile("" ::: "memory");

  #define BAR do { asm volatile("" ::: "memory"); __builtin_amdgcn_s_barrier(); \
                   asm volatile("" ::: "memory"); } while (0)
  #define MFMA16(mb_) do { __builtin_amdgcn_s_setprio(1);                        \
    _Pragma("unroll") for (int mm = 0; mm < 4; mm++)                             \
      _Pragma("unroll") for (int nn = 0; nn < 4; nn++)                           \
        acc[(mb_) + mm][nn] = __builtin_amdgcn_mfma_f32_16x16x32_bf16(           \
            af[mm], bg[nn], acc[(mb_) + mm][nn], 0, 0, 0);                       \
    __builtin_amdgcn_s_setprio(0); } while (0)

  for (int u = 0; u < NS; u++) {
    const u32 S = (u32)(u & 1) * 32768;
    u16* ldsO = &lds[(u32)((u & 1) ^ 1) * 32768];
    const bool st = (u + 1 < NS);
    const u32 kn  = (u32)((u + 1) & 7) * BK;                       // A col base, tile u+1
    const u32 bbn = (u32)(n0s + ((u + 1) >> 3)) * (BN * DIM) + kn; // B base, tile u+1

    bf16x8 af[4], bg[4];

    // ---- phase 0: reads A-k0 m0-3 + B-k0; stage A-k0(u+1); MFMA m0-3 kk0
    af[0] = *(const bf16x8*)&lds[S + aoff[0][0]];
    af[1] = *(const bf16x8*)&lds[S + aoff[0][1]];
    af[2] = *(const bf16x8*)&lds[S + aoff[0][2]];
    af[3] = *(const bf16x8*)&lds[S + aoff[0][3]];
    bg[0] = *(const bf16x8*)&lds[S + boff[0][0]];
    bg[1] = *(const bf16x8*)&lds[S + boff[0][1]];
    bg[2] = *(const bf16x8*)&lds[S + boff[0][2]];
    bg[3] = *(const bf16x8*)&lds[S + boff[0][3]];
    if (st) {
      gl_lds16(ebR + kn + gA0, ldsO + 0 * 4096 + t * 8);
      gl_lds16(ebR + kn + gA1, ldsO + 1 * 4096 + t * 8);
    }
    BAR;
    MFMA16(0);
    BAR;

    // ---- phase 1: reads A-k0 m4-7; stage B-k0(u+1); vmcnt(4); MFMA m4-7 kk0
    af[0] = *(const bf16x8*)&lds[S + aoff[0][4]];
    af[1] = *(const bf16x8*)&lds[S + aoff[0][5]];
    af[2] = *(const bf16x8*)&lds[S + aoff[0][6]];
    af[3] = *(const bf16x8*)&lds[S + aoff[0][7]];
    if (st) {
      gl_lds16(wb + bbn + gA0, ldsO + 16384 + 0 * 4096 + t * 8);
      gl_lds16(wb + bbn + gA1, ldsO + 16384 + 1 * 4096 + t * 8);
    }
    if (u == NS - 1) asm volatile("s_waitcnt vmcnt(0)" ::: "memory");
    else             asm volatile("s_waitcnt vmcnt(4)" ::: "memory");
    BAR;
    MFMA16(4);
    BAR;

    // ---- phase 2: reads A-k1 m0-3 + B-k1; stage A-k1(u+1); MFMA m0-3 kk1
    af[0] = *(const bf16x8*)&lds[S + aoff[1][0]];
    af[1] = *(const bf16x8*)&lds[S + aoff[1][1]];
    af[2] = *(const bf16x8*)&lds[S + aoff[1][2]];
    af[3] = *(const bf16x8*)&lds[S + aoff[1][3]];
    bg[0] = *(const bf16x8*)&lds[S + boff[1][0]];
    bg[1] = *(const bf16x8*)&lds[S + boff[1][1]];
    bg[2] = *(const bf16x8*)&lds[S + boff[1][2]];
    bg[3] = *(const bf16x8*)&lds[S + boff[1][3]];
    if (st) {
      gl_lds16(ebR + kn + 32 + gA0, ldsO + 2 * 4096 + t * 8);
      gl_lds16(ebR + kn + 32 + gA1, ldsO + 3 * 4096 + t * 8);
    }
    BAR;
    MFMA16(0);
    BAR;

    // ---- phase 3: reads A-k1 m4-7; stage B-k1(u+1); vmcnt(4); MFMA m4-7 kk1
    af[0] = *(const bf16x8*)&lds[S + aoff[1][4]];
    af[1] = *(const bf16x8*)&lds[S + aoff[1][5]];
    af[2] = *(const bf16x8*)&lds[S + aoff[1][6]];
    af[3] = *(const bf16x8*)&lds[S + aoff[1][7]];
    if (st) {
      gl_lds16(wb + bbn + 32 + gA0, ldsO + 16384 + 2 * 4096 + t * 8);
      gl_lds16(wb + bbn + 32 + gA1, ldsO + 16384 + 3 * 4096 + t * 8);
    }
    asm volatile("s_waitcnt vmcnt(4)" ::: "memory");
    BAR;
    MFMA16(4);
    BAR;

    if ((u & 7) == 7) {
      // epilogue for N-tile nt: clip, exp2, per-row partial; __syncthreads
      // drains vmcnt (resets count invariant; in-flight stages land anyway).
      const int nt = n0s + (u >> 3);
      #pragma unroll
      for (int m = 0; m < 8; m++) {
        #pragma unroll
        for (int q = 0; q < 4; q++) {
          float s = 0.f;
          #pragma unroll
          for (int n = 0; n < 4; n++) {
            float tc = __builtin_amdgcn_fmed3f(acc[m][n][q], CLIP_LO, CLIP_HI);
            s += __builtin_amdgcn_exp2f(__builtin_fmaf(tc, K1, -K1));
            acc[m][n][q] = 0.f;
          }
          s += __shfl_xor(s, 1, 64);
          s += __shfl_xor(s, 2, 64);
          s += __shfl_xor(s, 4, 64);
          s += __shfl_xor(s, 8, 64);
          if ((l & 15) == 0) ep[wn][wm * 128 + m * 16 + (l >> 4) * 4 + q] = s;
        }
      }
      __syncthreads();
      if (l < 32) {
        int r = w * 32 + l;
        float v = ep[0][r] + ep[1][r] + ep[2][r] + ep[3][r];
        psum[(size_t)nt * N_ROWS + rowbase + r] = v;
      }
      __syncthreads();
    }
  }
  #undef BAR
  #undef MFMA16
}

// ---- per-row LSE merge + margin swap + per-block loss sums ----
__global__ void arc_finish1(const float* __restrict__ psum, const float* __restrict__ ct,
                            float* __restrict__ bl) {
  int tid = threadIdx.x;
  int row = blockIdx.x * 256 + tid;
  float S = 0.f;
  for (int p = 0; p < NT2; p++) S += psum[(size_t)p * N_ROWS + row];
  float c  = __builtin_amdgcn_fmed3f(ct[row], CLIP_LO, CLIP_HI);
  float cm = c * COSM - sqrtf(fmaxf(1.0f - c * c, 0.0f)) * SINM;
  // swap the target's no-margin term for the margin term (both vs fixed max 64)
  float S2 = S - __builtin_amdgcn_exp2f(__builtin_fmaf(c,  K1, -K1))
               + __builtin_amdgcn_exp2f(__builtin_fmaf(cm, K1, -K1));
  float loss = 64.0f + __builtin_amdgcn_logf(S2) * 0.6931471805599453f - 64.0f * cm;
  #pragma unroll
  for (int off = 32; off; off >>= 1) loss += __shfl_xor(loss, off, 64);
  __shared__ float red[4];
  if ((tid & 63) == 0) red[tid >> 6] = loss;
  __syncthreads();
  if (tid == 0) bl[blockIdx.x] = red[0] + red[1] + red[2] + red[3];
}

__global__ void arc_finish2(const float* __restrict__ bl, float* __restrict__ out) {
  if (threadIdx.x == 0) {
    float t = 0.f;
    for (int i = 0; i < N_ROWS / 256; i++) t += bl[i];
    out[0] = t * (1.0f / (float)N_ROWS);
  }
}

extern "C" void kernel_launch(void* const* d_in, const int* in_sizes, int n_in,
                              void* d_out, int out_size, void* d_ws, size_t ws_size,
                              hipStream_t stream) {
  const float* emb   = (const float*)d_in[0];
  const int*   lab   = (const int*)d_in[1];
  const float* wts   = (const float*)d_in[2];

  char* ws = (char*)d_ws;
  u16*   wb    = (u16*)(ws);
  u16*   eb    = (u16*)(ws + WB_BYTES);
  float* psum  = (float*)(ws + WB_BYTES + EB_BYTES);
  float* ct    = (float*)(ws + WB_BYTES + EB_BYTES + PS_BYTES);
  float* bl    = (float*)(ws + WB_BYTES + EB_BYTES + PS_BYTES + CT_BYTES);
  int*   lab32 = (int*)  (ws + WB_BYTES + EB_BYTES + PS_BYTES + CT_BYTES + BL_BYTES);
  int*   flag  = (int*)  (ws + WB_BYTES + EB_BYTES + PS_BYTES + CT_BYTES + BL_BYTES + LAB_BYTES);
  // total ~37.1 MiB of d_ws assumed available

  lab_detect<<<dim3(1), dim3(1024), 0, stream>>>(lab, flag);
  lab_fix<<<dim3(N_ROWS / 256), dim3(256), 0, stream>>>(lab, flag, lab32);
  prep_w<<<dim3(CPAD / 4), dim3(256), 0, stream>>>(wts, wb);
  prep_e<<<dim3((N_ROWS * DIM / 8) / 256), dim3(256), 0, stream>>>(emb, eb);
  tgt_k<<<dim3(N_ROWS / 4), dim3(256), 0, stream>>>(emb, wts, lab32, ct);
  arc_main<<<dim3(16 * NSTRIPS), dim3(512), 0, stream>>>(eb, wb, psum);
  arc_finish1<<<dim3(N_ROWS / 256), dim3(256), 0, stream>>>(psum, ct, bl);
  arc_finish2<<<dim3(1), dim3(64), 0, stream>>>(bl, (float*)d_out);
}

// Round 10
// 212.365 us; speedup vs baseline: 1.7657x; 1.0205x over previous
//
#include <hip/hip_runtime.h>
#include <cstdint>
#include <cstddef>

// Problem constants (fixed by the reference)
#define N_ROWS 4096
#define DIM    512
#define NCLS   30000
#define BM 256
#define BN 256
#define BK 64
#define NT2  118                    // ceil(30000/256) N-tiles
#define CPAD (NT2 * 256)            // 30208, padded classes (zero rows)
#define SPT 2                       // N-tiles per block strip
#define NSTRIPS (NT2 / SPT)         // 59
#define NS  (SPT * (DIM / BK))      // 16 K-tiles per block

typedef float  f32x4  __attribute__((ext_vector_type(4)));
typedef short  bf16x8 __attribute__((ext_vector_type(8)));
typedef unsigned int   u32;
typedef unsigned short u16;

// ---- workspace layout (bytes) ----
#define WB_BYTES   ((size_t)CPAD * DIM * 2)     // 30,932,992
#define EB_BYTES   ((size_t)N_ROWS * DIM * 2)   //  4,194,304
#define PS_BYTES   ((size_t)NT2 * N_ROWS * 4)   //  1,933,312
#define CT_BYTES   ((size_t)N_ROWS * 4)
#define BL_BYTES   (64 * 4)
#define LAB_BYTES  ((size_t)N_ROWS * 4)

#define CLIP_HI ( 1.0f - 1e-7f)
#define CLIP_LO (-1.0f + 1e-7f)
#define COSM 0.8775825618903728f    // cos(0.5)
#define SINM 0.4794255386042030f    // sin(0.5)
#define K1   92.33248261972189f     // 64*log2(e): exp(64c-64) = 2^((c-1)*K1)

__device__ __forceinline__ u16 f2bf(float f) {  // RNE float->bf16
  u32 x = __builtin_bit_cast(u32, f);
  x += 0x7fffu + ((x >> 16) & 1u);
  return (u16)(x >> 16);
}

__device__ __forceinline__ void gl_lds16(const u16* g, u16* l) {
  __builtin_amdgcn_global_load_lds((const __attribute__((address_space(1))) u32*)g,
                                   (__attribute__((address_space(3))) u32*)l,
                                   16, 0, 0);
}

// ---- label dtype probe: int64 little-endian reads as [lo,0,lo,0,...] ----
__global__ void lab_detect(const int* __restrict__ lab, int* __restrict__ flag) {
  __shared__ int s_nz;
  int tid = threadIdx.x;
  if (tid == 0) s_nz = 0;
  __syncthreads();
  int nz = 0;
  for (int i = tid; i < N_ROWS / 2; i += 1024) nz |= lab[2 * i + 1];
  if (nz) atomicOr(&s_nz, 1);
  __syncthreads();
  if (tid == 0) *flag = (s_nz == 0) ? 1 : 0;   // 1 -> int64 layout
}

__global__ void lab_fix(const int* __restrict__ lab, const int* __restrict__ flag,
                        int* __restrict__ out) {
  int i = blockIdx.x * 256 + threadIdx.x;
  out[i] = flag[0] ? lab[2 * i] : lab[i];
}

// ---- W: L2-normalize rows + cast bf16; pad rows [NCLS,CPAD) with zeros ----
__global__ void prep_w(const float* __restrict__ w, u16* __restrict__ wb) {
  int wv   = threadIdx.x >> 6;
  int lane = threadIdx.x & 63;
  int c = blockIdx.x * 4 + wv;              // one wave per class row
  u16* dst = wb + (size_t)c * DIM + lane * 8;
  if (c >= NCLS) {
    *(uint4*)dst = make_uint4(0, 0, 0, 0);
    return;
  }
  const float* src = w + (size_t)c * DIM + lane * 8;
  float4 v0 = *(const float4*)src;
  float4 v1 = *(const float4*)(src + 4);
  float a[8] = {v0.x, v0.y, v0.z, v0.w, v1.x, v1.y, v1.z, v1.w};
  float ss = 0.f;
  #pragma unroll
  for (int i = 0; i < 8; i++) ss += a[i] * a[i];
  #pragma unroll
  for (int off = 32; off; off >>= 1) ss += __shfl_xor(ss, off, 64);
  float inv = 1.0f / fmaxf(sqrtf(ss), 1e-12f);
  union { u16 h[8]; uint4 q; } pk;
  #pragma unroll
  for (int i = 0; i < 8; i++) pk.h[i] = f2bf(a[i] * inv);
  *(uint4*)dst = pk.q;
}

// ---- E: cast bf16 ----
__global__ void prep_e(const float* __restrict__ e, u16* __restrict__ eb) {
  size_t idx = ((size_t)blockIdx.x * 256 + threadIdx.x) * 8;
  float4 v0 = *(const float4*)(e + idx);
  float4 v1 = *(const float4*)(e + idx + 4);
  float a[8] = {v0.x, v0.y, v0.z, v0.w, v1.x, v1.y, v1.z, v1.w};
  union { u16 h[8]; uint4 q; } pk;
  #pragma unroll
  for (int i = 0; i < 8; i++) pk.h[i] = f2bf(a[i]);
  *(uint4*)(eb + idx) = pk.q;
}

// ---- target cosine per row, f32: dot(emb[n], w[lab[n]]/||w[lab[n]]||) ----
__global__ void tgt_k(const float* __restrict__ emb, const float* __restrict__ wts,
                      const int* __restrict__ lab, float* __restrict__ ct) {
  int w = threadIdx.x >> 6, l = threadIdx.x & 63;
  int row = blockIdx.x * 4 + w;
  int c = lab[row];
  const float* e  = emb + (size_t)row * DIM + l * 8;
  const float* wp = wts + (size_t)c   * DIM + l * 8;
  float4 e0 = *(const float4*)e,       e1 = *(const float4*)(e + 4);
  float4 w0 = *(const float4*)wp,      w1 = *(const float4*)(wp + 4);
  float dot = e0.x*w0.x + e0.y*w0.y + e0.z*w0.z + e0.w*w0.w
            + e1.x*w1.x + e1.y*w1.y + e1.z*w1.z + e1.w*w1.w;
  float ss  = w0.x*w0.x + w0.y*w0.y + w0.z*w0.z + w0.w*w0.w
            + w1.x*w1.x + w1.y*w1.y + w1.z*w1.z + w1.w*w1.w;
  #pragma unroll
  for (int off = 32; off; off >>= 1) {
    dot += __shfl_xor(dot, off, 64);
    ss  += __shfl_xor(ss,  off, 64);
  }
  if (l == 0) ct[row] = dot / fmaxf(sqrtf(ss), 1e-12f);
}

// ---- fused GEMM + clip + partial sum-exp (fixed max = 64), 256x256 tile ----
// Deep-prefetch variant: A 2-buf (E is L2-hot, staged 1 tile ahead), B 3-buf
// ring (W is HBM-cold, staged 2 tiles ahead -> ~6 phases latency cover).
// LDS = 160 KB exactly. Quadrant phases: p0{a(m0-3)+b(n0-1), 12 rd} p1{b(n2-3)}
// p2{a(m4-7)} p3{none}; stages A->p0/p1, B->p2/p3; ONE vmcnt(4) per tile at p3
// (FIFO: leaves exactly B(u+2)x4 in flight -> never drains, incl. epilogues).
// Epilogue merges via dead A-buf1 (no __syncthreads, vmcnt untouched).
__global__ __launch_bounds__(512, 2) void arc_main(
    const u16* __restrict__ eb, const u16* __restrict__ wb,
    float* __restrict__ psum)
{
  __shared__ __align__(16) u16 lds[81920];   // A:2x32KB @0, B:3x32KB @65536B
  const int t  = threadIdx.x;
  const int l  = t & 63;
  const int w  = t >> 6;
  const int wm = w >> 2, wn = w & 3;
  const int cl = l & 15, bq = l >> 4;
  const int mi    = blockIdx.x & 15;
  const int strip = blockIdx.x >> 4;
  const int rowbase = mi * BM;
  const int n0s = strip * SPT;

  // frag LDS elem offsets (R6-verified): slot' = slot ^ (r&7)
  u32 aoff[16], boff[8];
  #pragma unroll
  for (int s = 0; s < 2; s++) {
    #pragma unroll
    for (int m = 0; m < 8; m++) {
      int r = wm * 128 + m * 16 + cl;
      aoff[s * 8 + m] = (u32)r * BK + (((s * 4 + bq) ^ (r & 7)) << 3);
    }
    #pragma unroll
    for (int n = 0; n < 4; n++) {
      int r = wn * 64 + n * 16 + cl;
      boff[s * 4 + n] = (u32)r * BK + (((s * 4 + bq) ^ (r & 7)) << 3);
    }
  }

  // staging (R6-verified): chunk c = rows [c*64, c*64+64), per-thread 16B;
  // linear LDS dest + inverse-swizzled global source (same involution).
  u32 goff[4];
  #pragma unroll
  for (int c = 0; c < 4; c++) {
    int rl = c * 64 + (t >> 3);
    goff[c] = (u32)rl * DIM + (((t & 7) ^ (rl & 7)) << 3);
  }
  const u16* ebR = eb + (size_t)rowbase * DIM;

  f32x4 acc[8][4];
  #pragma unroll
  for (int m = 0; m < 8; m++)
    #pragma unroll
    for (int n = 0; n < 4; n++)
      #pragma unroll
      for (int q = 0; q < 4; q++) acc[m][n][q] = 0.f;

  // prologue: A(0)->Abuf0, B(0)->Bbuf0, B(1)->Bbuf1; vmcnt(4) leaves B(1) flying
  {
    const u32 bb0 = (u32)n0s * (BN * DIM);
    #pragma unroll
    for (int c = 0; c < 4; c++)
      gl_lds16(ebR + goff[c], &lds[c * 4096 + w * 512]);
    #pragma unroll
    for (int c = 0; c < 4; c++)
      gl_lds16(wb + bb0 + goff[c], &lds[32768 + c * 4096 + w * 512]);
    #pragma unroll
    for (int c = 0; c < 4; c++)
      gl_lds16(wb + bb0 + BK + goff[c], &lds[49152 + c * 4096 + w * 512]);
  }
  asm volatile("s_waitcnt vmcnt(4)" ::: "memory");
  __builtin_amdgcn_s_barrier();
  asm volatile("" ::: "memory");

  #define BAR do { asm volatile("" ::: "memory"); __builtin_amdgcn_s_barrier(); \
                   asm volatile("" ::: "memory"); } while (0)

  for (int u = 0; u < NS; u++) {
    const u16* As = &lds[(u32)(u & 1) * 16384];
    const u16* Bs = &lds[32768 + (u32)(u % 3) * 16384];
    u16* An = &lds[(u32)((u + 1) & 1) * 16384];
    u16* Bn = &lds[32768 + (u32)((u + 2) % 3) * 16384];
    const bool stA = (u + 1 < NS);
    const bool stB = (u + 2 < NS);
    const u32 kA = (u32)((u + 1) & 7) * BK;
    const u32 bB = (u32)(n0s + ((u + 2) >> 3)) * (BN * DIM) + (u32)((u + 2) & 7) * BK;

    bf16x8 a03[2][4], a47[2][4], b01[2][2], b23[2][2];

    // ---- p0: read a(m0-3)+b(n0-1) both kk (12); stage A c0-1; MFMA m0-3 x n0-1
    #pragma unroll
    for (int kk = 0; kk < 2; kk++) {
      #pragma unroll
      for (int m = 0; m < 4; m++) a03[kk][m] = *(const bf16x8*)&As[aoff[kk * 8 + m]];
      b01[kk][0] = *(const bf16x8*)&Bs[boff[kk * 4 + 0]];
      b01[kk][1] = *(const bf16x8*)&Bs[boff[kk * 4 + 1]];
    }
    if (stA) {
      gl_lds16(ebR + kA + goff[0], An + 0 * 4096 + w * 512);
      gl_lds16(ebR + kA + goff[1], An + 1 * 4096 + w * 512);
    }
    BAR;
    asm volatile("s_waitcnt lgkmcnt(0)" ::: "memory");
    __builtin_amdgcn_s_setprio(1);
    #pragma unroll
    for (int kk = 0; kk < 2; kk++)
      #pragma unroll
      for (int m = 0; m < 4; m++)
        #pragma unroll
        for (int n = 0; n < 2; n++)
          acc[m][n] = __builtin_amdgcn_mfma_f32_16x16x32_bf16(a03[kk][m], b01[kk][n], acc[m][n], 0, 0, 0);
    __builtin_amdgcn_s_setprio(0);
    BAR;

    // ---- p1: read b(n2-3) (4); stage A c2-3; MFMA m0-3 x n2-3 ----
    #pragma unroll
    for (int kk = 0; kk < 2; kk++) {
      b23[kk][0] = *(const bf16x8*)&Bs[boff[kk * 4 + 2]];
      b23[kk][1] = *(const bf16x8*)&Bs[boff[kk * 4 + 3]];
    }
    if (stA) {
      gl_lds16(ebR + kA + goff[2], An + 2 * 4096 + w * 512);
      gl_lds16(ebR + kA + goff[3], An + 3 * 4096 + w * 512);
    }
    BAR;
    asm volatile("s_waitcnt lgkmcnt(0)" ::: "memory");
    __builtin_amdgcn_s_setprio(1);
    #pragma unroll
    for (int kk = 0; kk < 2; kk++)
      #pragma unroll
      for (int m = 0; m < 4; m++)
        #pragma unroll
        for (int n = 0; n < 2; n++)
          acc[m][n + 2] = __builtin_amdgcn_mfma_f32_16x16x32_bf16(a03[kk][m], b23[kk][n], acc[m][n + 2], 0, 0, 0);
    __builtin_amdgcn_s_setprio(0);
    BAR;

    // ---- p2: read a(m4-7) (8); stage B c0-1 (tile u+2); MFMA m4-7 x n0-1 ----
    #pragma unroll
    for (int kk = 0; kk < 2; kk++)
      #pragma unroll
      for (int m = 0; m < 4; m++) a47[kk][m] = *(const bf16x8*)&As[aoff[kk * 8 + 4 + m]];
    if (stB) {
      gl_lds16(wb + bB + goff[0], Bn + 0 * 4096 + w * 512);
      gl_lds16(wb + bB + goff[1], Bn + 1 * 4096 + w * 512);
    }
    BAR;
    asm volatile("s_waitcnt lgkmcnt(0)" ::: "memory");
    __builtin_amdgcn_s_setprio(1);
    #pragma unroll
    for (int kk = 0; kk < 2; kk++)
      #pragma unroll
      for (int m = 0; m < 4; m++)
        #pragma unroll
        for (int n = 0; n < 2; n++)
          acc[4 + m][n] = __builtin_amdgcn_mfma_f32_16x16x32_bf16(a47[kk][m], b01[kk][n], acc[4 + m][n], 0, 0, 0);
    __builtin_amdgcn_s_setprio(0);
    BAR;

    // ---- p3: no reads; stage B c2-3; vmcnt(4); MFMA m4-7 x n2-3 ----
    if (stB) {
      gl_lds16(wb + bB + goff[2], Bn + 2 * 4096 + w * 512);
      gl_lds16(wb + bB + goff[3], Bn + 3 * 4096 + w * 512);
    }
    if (u >= NS - 2) asm volatile("s_waitcnt vmcnt(0)" ::: "memory");
    else             asm volatile("s_waitcnt vmcnt(4)" ::: "memory");
    BAR;
    __builtin_amdgcn_s_setprio(1);
    #pragma unroll
    for (int kk = 0; kk < 2; kk++)
      #pragma unroll
      for (int m = 0; m < 4; m++)
        #pragma unroll
        for (int n = 0; n < 2; n++)
          acc[4 + m][n + 2] = __builtin_amdgcn_mfma_f32_16x16x32_bf16(a47[kk][m], b23[kk][n], acc[4 + m][n + 2], 0, 0, 0);
    __builtin_amdgcn_s_setprio(0);
    BAR;

    if ((u & 7) == 7) {
      // epilogue for N-tile nt via dead A-buf1 (u odd here -> A(u) buf is buf1,
      // fully read; in-flight stages target Abuf0/B-ring, never buf1).
      const int nt = n0s + (u >> 3);
      float* epf = (float*)&lds[16384];
      #pragma unroll
      for (int m = 0; m < 8; m++) {
        #pragma unroll
        for (int q = 0; q < 4; q++) {
          float s = 0.f;
          #pragma unroll
          for (int n = 0; n < 4; n++) {
            float tc = __builtin_amdgcn_fmed3f(acc[m][n][q], CLIP_LO, CLIP_HI);
            s += __builtin_amdgcn_exp2f(__builtin_fmaf(tc, K1, -K1));
            acc[m][n][q] = 0.f;
          }
          s += __shfl_xor(s, 1, 64);
          s += __shfl_xor(s, 2, 64);
          s += __shfl_xor(s, 4, 64);
          s += __shfl_xor(s, 8, 64);
          if ((l & 15) == 0) epf[wn * 256 + wm * 128 + m * 16 + (l >> 4) * 4 + q] = s;
        }
      }
      asm volatile("s_waitcnt lgkmcnt(0)" ::: "memory");
      __builtin_amdgcn_s_barrier();
      asm volatile("" ::: "memory");
      if (l < 32) {
        int r = w * 32 + l;
        float v = epf[r] + epf[256 + r] + epf[512 + r] + epf[768 + r];
        psum[(size_t)nt * N_ROWS + rowbase + r] = v;
      }
      asm volatile("s_waitcnt lgkmcnt(0)" ::: "memory");
      __builtin_amdgcn_s_barrier();
      asm volatile("" ::: "memory");
    }
  }
  #undef BAR
}

// ---- per-row LSE merge + margin swap + per-block loss sums ----
__global__ void arc_finish1(const float* __restrict__ psum, const float* __restrict__ ct,
                            float* __restrict__ bl) {
  int tid = threadIdx.x;
  int row = blockIdx.x * 256 + tid;
  float S = 0.f;
  for (int p = 0; p < NT2; p++) S += psum[(size_t)p * N_ROWS + row];
  float c  = __builtin_amdgcn_fmed3f(ct[row], CLIP_LO, CLIP_HI);
  float cm = c * COSM - sqrtf(fmaxf(1.0f - c * c, 0.0f)) * SINM;
  // swap the target's no-margin term for the margin term (both vs fixed max 64)
  float S2 = S - __builtin_amdgcn_exp2f(__builtin_fmaf(c,  K1, -K1))
               + __builtin_amdgcn_exp2f(__builtin_fmaf(cm, K1, -K1));
  float loss = 64.0f + __builtin_amdgcn_logf(S2) * 0.6931471805599453f - 64.0f * cm;
  #pragma unroll
  for (int off = 32; off; off >>= 1) loss += __shfl_xor(loss, off, 64);
  __shared__ float red[4];
  if ((tid & 63) == 0) red[tid >> 6] = loss;
  __syncthreads();
  if (tid == 0) bl[blockIdx.x] = red[0] + red[1] + red[2] + red[3];
}

__global__ void arc_finish2(const float* __restrict__ bl, float* __restrict__ out) {
  if (threadIdx.x == 0) {
    float t = 0.f;
    for (int i = 0; i < N_ROWS / 256; i++) t += bl[i];
    out[0] = t * (1.0f / (float)N_ROWS);
  }
}

extern "C" void kernel_launch(void* const* d_in, const int* in_sizes, int n_in,
                              void* d_out, int out_size, void* d_ws, size_t ws_size,
                              hipStream_t stream) {
  const float* emb   = (const float*)d_in[0];
  const int*   lab   = (const int*)d_in[1];
  const float* wts   = (const float*)d_in[2];

  char* ws = (char*)d_ws;
  u16*   wb    = (u16*)(ws);
  u16*   eb    = (u16*)(ws + WB_BYTES);
  float* psum  = (float*)(ws + WB_BYTES + EB_BYTES);
  float* ct    = (float*)(ws + WB_BYTES + EB_BYTES + PS_BYTES);
  float* bl    = (float*)(ws + WB_BYTES + EB_BYTES + PS_BYTES + CT_BYTES);
  int*   lab32 = (int*)  (ws + WB_BYTES + EB_BYTES + PS_BYTES + CT_BYTES + BL_BYTES);
  int*   flag  = (int*)  (ws + WB_BYTES + EB_BYTES + PS_BYTES + CT_BYTES + BL_BYTES + LAB_BYTES);
  // total ~37.1 MiB of d_ws assumed available

  lab_detect<<<dim3(1), dim3(1024), 0, stream>>>(lab, flag);
  lab_fix<<<dim3(N_ROWS / 256), dim3(256), 0, stream>>>(lab, flag, lab32);
  prep_w<<<dim3(CPAD / 4), dim3(256), 0, stream>>>(wts, wb);
  prep_e<<<dim3((N_ROWS * DIM / 8) / 256), dim3(256), 0, stream>>>(emb, eb);
  tgt_k<<<dim3(N_ROWS / 4), dim3(256), 0, stream>>>(emb, wts, lab32, ct);
  arc_main<<<dim3(16 * NSTRIPS), dim3(512), 0, stream>>>(eb, wb, psum);
  arc_finish1<<<dim3(N_ROWS / 256), dim3(256), 0, stream>>>(psum, ct, bl);
  arc_finish2<<<dim3(1), dim3(64), 0, stream>>>(bl, (float*)d_out);
}